// Round 1
// baseline (1042.377 us; speedup 1.0000x reference)
//
#include <hip/hip_runtime.h>
#include <stdint.h>

typedef int v4i __attribute__((ext_vector_type(4)));

#define GLD_LDS16(g, l) __builtin_amdgcn_global_load_lds( \
    (const __attribute__((address_space(1))) void*)(g),   \
    (__attribute__((address_space(3))) void*)(l), 16, 0, 0)

__device__ __forceinline__ float wsum(float v){
  #pragma unroll
  for (int o = 32; o; o >>= 1) v += __shfl_xor(v, o, 64);
  return v;
}
__device__ __forceinline__ float wmaxr(float v){
  #pragma unroll
  for (int o = 32; o; o >>= 1) v = fmaxf(v, __shfl_xor(v, o, 64));
  return v;
}
__device__ __forceinline__ float gelu_f(float x){
  return 0.5f * x * (1.0f + erff(x * 0.7071067811865476f));
}

// ---------------- LayerNorm absmax (pass 1: no store) ----------------
__global__ __launch_bounds__(256) void k_ln_absmax(
    const float* __restrict__ x, const float* __restrict__ gamma,
    const float* __restrict__ beta, unsigned int* __restrict__ smax_out, int M)
{
  __shared__ float red[4];
  const int lane = threadIdx.x & 63, wave = threadIdx.x >> 6;
  float lmax = 0.f;
  for (int row = blockIdx.x * 4 + wave; row < M; row += gridDim.x * 4) {
    const float4* xr = (const float4*)(x + (size_t)row * 1024);
    float4 v[4]; float s = 0.f;
    #pragma unroll
    for (int j = 0; j < 4; j++){ v[j] = xr[j*64 + lane]; s += v[j].x+v[j].y+v[j].z+v[j].w; }
    s = wsum(s);
    const float mu = s * (1.f/1024.f);
    float sq = 0.f;
    #pragma unroll
    for (int j = 0; j < 4; j++){
      float a=v[j].x-mu, b=v[j].y-mu, c=v[j].z-mu, d=v[j].w-mu;
      sq += a*a + b*b + c*c + d*d;
    }
    sq = wsum(sq);
    const float rs = 1.0f / sqrtf(sq * (1.f/1024.f) + 1e-5f);
    #pragma unroll
    for (int j = 0; j < 4; j++){
      int c0 = j*256 + lane*4;
      float4 g = *(const float4*)(gamma + c0);
      float4 b = *(const float4*)(beta + c0);
      float y0=(v[j].x-mu)*rs*g.x+b.x, y1=(v[j].y-mu)*rs*g.y+b.y;
      float y2=(v[j].z-mu)*rs*g.z+b.z, y3=(v[j].w-mu)*rs*g.w+b.w;
      lmax = fmaxf(lmax, fmaxf(fmaxf(fabsf(y0),fabsf(y1)), fmaxf(fabsf(y2),fabsf(y3))));
    }
  }
  lmax = wmaxr(lmax);
  if (lane == 0) red[wave] = lmax;
  __syncthreads();
  if (threadIdx.x == 0)
    atomicMax(smax_out, __float_as_uint(fmaxf(fmaxf(red[0],red[1]), fmaxf(red[2],red[3]))));
}

// ---------------- LayerNorm + quantize to int8 (pass 2) ----------------
__global__ __launch_bounds__(256) void k_ln_quant(
    const float* __restrict__ x, const float* __restrict__ gamma,
    const float* __restrict__ beta, const unsigned int* __restrict__ sbits,
    signed char* __restrict__ A1, int M)
{
  const float s = fmaxf(__uint_as_float(*sbits), 1e-12f);
  const int lane = threadIdx.x & 63, wave = threadIdx.x >> 6;
  for (int row = blockIdx.x * 4 + wave; row < M; row += gridDim.x * 4) {
    const float4* xr = (const float4*)(x + (size_t)row * 1024);
    float4 v[4]; float sm = 0.f;
    #pragma unroll
    for (int j = 0; j < 4; j++){ v[j] = xr[j*64 + lane]; sm += v[j].x+v[j].y+v[j].z+v[j].w; }
    sm = wsum(sm);
    const float mu = sm * (1.f/1024.f);
    float sq = 0.f;
    #pragma unroll
    for (int j = 0; j < 4; j++){
      float a=v[j].x-mu, b=v[j].y-mu, c=v[j].z-mu, d=v[j].w-mu;
      sq += a*a + b*b + c*c + d*d;
    }
    sq = wsum(sq);
    const float rs = 1.0f / sqrtf(sq * (1.f/1024.f) + 1e-5f);
    #pragma unroll
    for (int j = 0; j < 4; j++){
      int c0 = j*256 + lane*4;
      float4 g = *(const float4*)(gamma + c0);
      float4 b = *(const float4*)(beta + c0);
      float y0=(v[j].x-mu)*rs*g.x+b.x, y1=(v[j].y-mu)*rs*g.y+b.y;
      float y2=(v[j].z-mu)*rs*g.z+b.z, y3=(v[j].w-mu)*rs*g.w+b.w;
      char4 qc;
      qc.x = (signed char)(int)rintf(fminf(fmaxf(y0/s,-1.f),1.f)*127.f);
      qc.y = (signed char)(int)rintf(fminf(fmaxf(y1/s,-1.f),1.f)*127.f);
      qc.z = (signed char)(int)rintf(fminf(fmaxf(y2/s,-1.f),1.f)*127.f);
      qc.w = (signed char)(int)rintf(fminf(fmaxf(y3/s,-1.f),1.f)*127.f);
      *(char4*)(A1 + (size_t)row*1024 + c0) = qc;
    }
  }
}

// ---------------- generic absmax over fp32 array ----------------
__global__ __launch_bounds__(256) void k_absmax(
    const float* __restrict__ w, long n4, unsigned int* __restrict__ out)
{
  __shared__ float red[4];
  const int lane = threadIdx.x & 63, wave = threadIdx.x >> 6;
  float lmax = 0.f;
  for (long i = blockIdx.x*256 + threadIdx.x; i < n4; i += (long)gridDim.x*256) {
    float4 v = ((const float4*)w)[i];
    lmax = fmaxf(lmax, fmaxf(fmaxf(fabsf(v.x),fabsf(v.y)), fmaxf(fabsf(v.z),fabsf(v.w))));
  }
  lmax = wmaxr(lmax);
  if (lane == 0) red[wave] = lmax;
  __syncthreads();
  if (threadIdx.x == 0)
    atomicMax(out, __float_as_uint(fmaxf(fmaxf(red[0],red[1]), fmaxf(red[2],red[3]))));
}

// ---------------- weight quantize to int8 ----------------
__global__ __launch_bounds__(256) void k_wquant(
    const float* __restrict__ w, long n4, const unsigned int* __restrict__ sbits,
    signed char* __restrict__ wq)
{
  const float s = fmaxf(__uint_as_float(*sbits), 1e-12f);
  for (long i = blockIdx.x*256 + threadIdx.x; i < n4; i += (long)gridDim.x*256) {
    float4 v = ((const float4*)w)[i];
    char4 qc;
    qc.x = (signed char)(int)rintf(fminf(fmaxf(v.x/s,-1.f),1.f)*127.f);
    qc.y = (signed char)(int)rintf(fminf(fmaxf(v.y/s,-1.f),1.f)*127.f);
    qc.z = (signed char)(int)rintf(fminf(fmaxf(v.z/s,-1.f),1.f)*127.f);
    qc.w = (signed char)(int)rintf(fminf(fmaxf(v.w/s,-1.f),1.f)*127.f);
    *(char4*)(wq + i*4) = qc;
  }
}

// ---------------- int8 GEMM, m97-style 128x128 tile, BK=64 ----------------
// out[m,n] = sum_k A[m,k]*W[n,k]  (both K-minor row-major, NT)
// MODE 0: epilogue = dequant+bias+gelu, global absmax only (no store)
// MODE 1: epilogue = dequant+bias+gelu, quantize by scales[ig], store int8
// MODE 2: epilogue = dequant+bias, store fp32
template<int MODE>
__global__ __launch_bounds__(256, 2) void k_gemm_i8(
    const signed char* __restrict__ A, const signed char* __restrict__ W,
    const float* __restrict__ bias, const unsigned int* __restrict__ scales,
    float* __restrict__ outf, signed char* __restrict__ outq,
    unsigned int* __restrict__ gmax,
    int M, int N, int K, int ia, int iw, int ig)
{
  __shared__ __align__(16) signed char As[128*64];
  __shared__ __align__(16) signed char Bs[128*64];
  __shared__ float red[4];

  // bijective XCD swizzle (m204)
  const int nwg = gridDim.x, orig = blockIdx.x;
  const int q8 = nwg >> 3, r8 = nwg & 7;
  const int xcd = orig & 7, idx = orig >> 3;
  const int wgid = (xcd < r8 ? xcd*(q8+1) : r8*(q8+1) + (xcd-r8)*q8) + idx;

  const int tn = N >> 7;
  const int bm = wgid / tn, bn = wgid % tn;
  const int tid = threadIdx.x, lane = tid & 63, wave = tid >> 6;
  const int wm = wave >> 1, wn = wave & 1;
  const size_t row0 = (size_t)bm * 128, col0 = (size_t)bn * 128;

  v4i acc[4][4];
  #pragma unroll
  for (int i = 0; i < 4; i++)
    #pragma unroll
    for (int j = 0; j < 4; j++) acc[i][j] = (v4i){0,0,0,0};

  const int ksteps = K >> 6;
  for (int kt = 0; kt < ksteps; ++kt) {
    const size_t kb = (size_t)kt << 6;
    #pragma unroll
    for (int i = 0; i < 2; i++) {
      const int chunk = i*4 + wave;            // 1024B per wave-chunk
      const int off = chunk*1024 + lane*16;    // flat byte offset in 128x64 tile
      const int r = off >> 6, kk = off & 63;
      GLD_LDS16(A + (row0 + r)*(size_t)K + kb + kk, As + chunk*1024);
      GLD_LDS16(W + (col0 + r)*(size_t)K + kb + kk, Bs + chunk*1024);
    }
    __syncthreads();

    v4i af[4], bf[4];
    #pragma unroll
    for (int mi = 0; mi < 4; mi++)
      af[mi] = *(const v4i*)(As + ((wm*64 + mi*16 + (lane & 15)) << 6) + ((lane >> 4) << 4));
    #pragma unroll
    for (int ni = 0; ni < 4; ni++)
      bf[ni] = *(const v4i*)(Bs + ((wn*64 + ni*16 + (lane & 15)) << 6) + ((lane >> 4) << 4));
    #pragma unroll
    for (int mi = 0; mi < 4; mi++)
      #pragma unroll
      for (int ni = 0; ni < 4; ni++)
        acc[mi][ni] = __builtin_amdgcn_mfma_i32_16x16x64_i8(af[mi], bf[ni], acc[mi][ni], 0, 0, 0);
    __syncthreads();
  }

  // epilogue
  const float sa = fmaxf(__uint_as_float(scales[ia]), 1e-12f);
  const float sw = fmaxf(__uint_as_float(scales[iw]), 1e-12f);
  const float sc = (sa / 127.f) * (sw / 127.f);
  const int rowbase = (int)row0 + wm*64;
  const int colbase = (int)col0 + wn*64;

  if (MODE == 0) {
    float lmax = 0.f;
    #pragma unroll
    for (int mi = 0; mi < 4; mi++)
      #pragma unroll
      for (int ni = 0; ni < 4; ni++) {
        const int colc = colbase + ni*16 + (lane & 15);
        const float b = bias[colc];
        #pragma unroll
        for (int j = 0; j < 4; j++) {
          float g = gelu_f((float)acc[mi][ni][j] * sc + b);
          lmax = fmaxf(lmax, fabsf(g));
        }
      }
    lmax = wmaxr(lmax);
    if (lane == 0) red[wave] = lmax;
    __syncthreads();
    if (tid == 0)
      atomicMax(gmax, __float_as_uint(fmaxf(fmaxf(red[0],red[1]), fmaxf(red[2],red[3]))));
  } else if (MODE == 1) {
    const float sg = fmaxf(__uint_as_float(scales[ig]), 1e-12f);
    #pragma unroll
    for (int mi = 0; mi < 4; mi++)
      #pragma unroll
      for (int ni = 0; ni < 4; ni++) {
        const int colc = colbase + ni*16 + (lane & 15);
        const float b = bias[colc];
        #pragma unroll
        for (int j = 0; j < 4; j++) {
          const int row = rowbase + mi*16 + ((lane >> 4) << 2) + j;
          float g = gelu_f((float)acc[mi][ni][j] * sc + b);
          float t = fminf(fmaxf(g / sg, -1.f), 1.f) * 127.f;
          outq[(size_t)row * N + colc] = (signed char)(int)rintf(t);
        }
      }
  } else {
    #pragma unroll
    for (int mi = 0; mi < 4; mi++)
      #pragma unroll
      for (int ni = 0; ni < 4; ni++) {
        const int colc = colbase + ni*16 + (lane & 15);
        const float b = bias[colc];
        #pragma unroll
        for (int j = 0; j < 4; j++) {
          const int row = rowbase + mi*16 + ((lane >> 4) << 2) + j;
          outf[(size_t)row * N + colc] = (float)acc[mi][ni][j] * sc + b;
        }
      }
  }
}

extern "C" void kernel_launch(void* const* d_in, const int* in_sizes, int n_in,
                              void* d_out, int out_size, void* d_ws, size_t ws_size,
                              hipStream_t stream)
{
  const float* x     = (const float*)d_in[0];
  const float* gamma = (const float*)d_in[1];
  const float* beta  = (const float*)d_in[2];
  const float* w1    = (const float*)d_in[3];
  const float* b1    = (const float*)d_in[4];
  const float* w2    = (const float*)d_in[5];
  const float* b2    = (const float*)d_in[6];
  float* out = (float*)d_out;

  const int D = 1024;
  const int M = in_sizes[0] / D;   // 32768
  const int H = in_sizes[3] / D;   // 4096

  char* ws = (char*)d_ws;
  unsigned int* scales = (unsigned int*)ws;         // [0]=sa_ln [1]=sw1 [2]=sw2 [3]=s_gelu
  signed char* A1  = (signed char*)(ws + 256);      // M x D
  signed char* w1q = A1 + (size_t)M * D;            // H x D
  signed char* w2q = w1q + (size_t)H * D;           // D x H
  signed char* A2  = w2q + (size_t)H * D;           // M x H

  hipMemsetAsync(scales, 0, 32, stream);
  k_absmax<<<512, 256, 0, stream>>>(w1, (long)H * D / 4, scales + 1);
  k_absmax<<<512, 256, 0, stream>>>(w2, (long)H * D / 4, scales + 2);
  k_ln_absmax<<<4096, 256, 0, stream>>>(x, gamma, beta, scales, M);
  k_wquant<<<512, 256, 0, stream>>>(w1, (long)H * D / 4, scales + 1, w1q);
  k_wquant<<<512, 256, 0, stream>>>(w2, (long)H * D / 4, scales + 2, w2q);
  k_ln_quant<<<4096, 256, 0, stream>>>(x, gamma, beta, scales, A1, M);

  const int g1 = (M / 128) * (H / 128);   // 8192
  k_gemm_i8<0><<<g1, 256, 0, stream>>>(A1, w1q, b1, scales, nullptr, nullptr,
                                       scales + 3, M, H, D, 0, 1, 0);
  k_gemm_i8<1><<<g1, 256, 0, stream>>>(A1, w1q, b1, scales, nullptr, A2,
                                       nullptr, M, H, D, 0, 1, 3);
  const int g2 = (M / 128) * (D / 128);   // 2048
  k_gemm_i8<2><<<g2, 256, 0, stream>>>(A2, w2q, b2, scales, out, nullptr,
                                       nullptr, M, D, H, 3, 2, 0);
}